// Round 9
// baseline (1141.369 us; speedup 1.0000x reference)
//
#include <hip/hip_runtime.h>

// LightGCN on MI355X, round 8 (resubmit — round-8 bench was an infra failure).
// Build made write-coalesced: p_part and p_bsort stage an LDS permutation and
// emit ordered (streaming) global writes instead of LDS-cursor random scatter.
// k_cvt fused into p_part's grid. Gather (8 lanes/edge, uint4, bf16) unchanged.

static constexpr int D     = 64;
static constexpr int BLK   = 256;
static constexpr int WPB   = BLK / 64;   // nodes per gather block
static constexpr int CHUNK = 16384;      // edges per partition chunk
static constexpr int NBK   = 512;        // nodes per bucket (dst>>9)
static constexpr int MAXNB = 1024;
static constexpr int PERMCAP = 18432;    // p_bsort perm capacity (16384 + 16 sigma)
static constexpr int CVTB  = 256;        // cvt blocks appended to p_part grid

typedef unsigned long long u64;
typedef unsigned short u16;

__device__ __forceinline__ float4 ldf4(const float* p) {
    return *reinterpret_cast<const float4*>(p);
}
__device__ __forceinline__ u16 f2b(float f) {          // f32 -> bf16 (RNE)
    unsigned u = __float_as_uint(f);
    return (u16)((u + 0x7FFFu + ((u >> 16) & 1u)) >> 16);
}
__device__ __forceinline__ float blo(unsigned u) {
    return __uint_as_float(u << 16);
}
__device__ __forceinline__ float bhi(unsigned u) {
    return __uint_as_float(u & 0xFFFF0000u);
}

// ---- pass A: per-chunk histogram over coarse buckets ----
__global__ __launch_bounds__(512)
void p_hist(const int* __restrict__ edst, unsigned* __restrict__ cnt,
            int E, int NB, int nchunk) {
    __shared__ unsigned h[MAXNB];
    const int c = blockIdx.x;
    for (int j = threadIdx.x; j < NB; j += 512) h[j] = 0u;
    __syncthreads();
    const long long base = (long long)c * CHUNK;
    const int lim = (int)min((long long)CHUNK, (long long)E - base);
    const int nv = lim >> 2;
    const int4* d4 = (const int4*)(edst + base);
    for (int i = threadIdx.x; i < nv; i += 512) {
        int4 d = d4[i];
        atomicAdd(&h[(unsigned)d.x >> 9], 1u);
        atomicAdd(&h[(unsigned)d.y >> 9], 1u);
        atomicAdd(&h[(unsigned)d.z >> 9], 1u);
        atomicAdd(&h[(unsigned)d.w >> 9], 1u);
    }
    for (int i = (nv << 2) + threadIdx.x; i < lim; i += 512)
        atomicAdd(&h[(unsigned)edst[base + i] >> 9], 1u);
    __syncthreads();
    for (int j = threadIdx.x; j < NB; j += 512)
        cnt[(size_t)j * nchunk + c] = h[j];
}

// ---- scan pass 1: per-1024-block reduce ----
__global__ __launch_bounds__(1024)
void p_reduce(const unsigned* __restrict__ cnt, unsigned* __restrict__ bsum, int M) {
    __shared__ unsigned wsum[16];
    int i = blockIdx.x * 1024 + threadIdx.x;
    unsigned v = (i < M) ? cnt[i] : 0u;
    #pragma unroll
    for (int d = 1; d < 64; d <<= 1) v += __shfl_xor(v, d);
    if ((threadIdx.x & 63) == 0) wsum[threadIdx.x >> 6] = v;
    __syncthreads();
    if (threadIdx.x < 16) {
        unsigned x = wsum[threadIdx.x];
        #pragma unroll
        for (int d = 1; d < 16; d <<= 1) x += __shfl_xor(x, d);
        if (threadIdx.x == 0) bsum[blockIdx.x] = x;
    }
}

// ---- scan pass 2: single-block exclusive scan (small arrays) ----
__global__ __launch_bounds__(1024)
void k_scan(const unsigned* __restrict__ cnt, unsigned* __restrict__ off, int N) {
    __shared__ unsigned wsum[16];
    __shared__ unsigned carry_s;
    const int lane = threadIdx.x & 63;
    const int w    = threadIdx.x >> 6;
    if (threadIdx.x == 0) carry_s = 0;
    __syncthreads();
    for (int base = 0; base < N; base += 1024) {
        int i = base + (int)threadIdx.x;
        unsigned v = (i < N) ? cnt[i] : 0u;
        unsigned inc = v;
        #pragma unroll
        for (int d = 1; d < 64; d <<= 1) {
            unsigned t = __shfl_up(inc, d);
            if (lane >= d) inc += t;
        }
        if (lane == 63) wsum[w] = inc;
        __syncthreads();
        if (threadIdx.x < 16) {
            unsigned x = wsum[threadIdx.x];
            #pragma unroll
            for (int d = 1; d < 16; d <<= 1) {
                unsigned t = __shfl_up(x, d);
                if ((int)threadIdx.x >= d) x += t;
            }
            wsum[threadIdx.x] = x;
        }
        __syncthreads();
        unsigned carry = carry_s;
        unsigned woff  = (w == 0) ? 0u : wsum[w - 1];
        if (i < N) off[i] = carry + woff + inc - v;
        __syncthreads();
        if (threadIdx.x == 1023) carry_s = carry + wsum[15];
        __syncthreads();
    }
    if (threadIdx.x == 0) off[N] = carry_s;
}

// ---- scan pass 3: block exclusive scan + block base, in place ----
__global__ __launch_bounds__(1024)
void p_scanapply(unsigned* __restrict__ cnt, const unsigned* __restrict__ bsumX, int M) {
    __shared__ unsigned wsum[16];
    const int lane = threadIdx.x & 63;
    const int w    = threadIdx.x >> 6;
    int i = blockIdx.x * 1024 + threadIdx.x;
    unsigned v = (i < M) ? cnt[i] : 0u;
    unsigned inc = v;
    #pragma unroll
    for (int d = 1; d < 64; d <<= 1) {
        unsigned t = __shfl_up(inc, d);
        if (lane >= d) inc += t;
    }
    if (lane == 63) wsum[w] = inc;
    __syncthreads();
    if (threadIdx.x < 16) {
        unsigned x = wsum[threadIdx.x];
        #pragma unroll
        for (int d = 1; d < 16; d <<= 1) {
            unsigned t = __shfl_up(x, d);
            if ((int)threadIdx.x >= d) x += t;
        }
        wsum[threadIdx.x] = x;
    }
    __syncthreads();
    unsigned excl = inc - v + ((w == 0) ? 0u : wsum[w - 1]) + bsumX[blockIdx.x];
    if (i < M) cnt[i] = excl;
}

// ---- pass C (v3): perm-staged partition + fused bf16 cvt blocks ----
__global__ __launch_bounds__(512)
void p_part(const int* __restrict__ esrc, const int* __restrict__ edst,
            const float* __restrict__ ev, const unsigned* __restrict__ cnt,
            u64* __restrict__ tmp,
            const float* __restrict__ ue, const float* __restrict__ ie,
            u16* __restrict__ x0, long long u_elems, long long total4,
            int E, int NB, int nchunk) {
    if ((int)blockIdx.x >= nchunk) {
        // fused cvt: concat(ue,ie) -> bf16 x0
        const long long stride = (long long)CVTB * 512;
        for (long long i = (long long)(blockIdx.x - nchunk) * 512 + threadIdx.x;
             i < total4; i += stride) {
            long long idx = i * 4;
            float4 b = (idx < u_elems) ? ldf4(ue + idx) : ldf4(ie + (idx - u_elems));
            ushort4 o;
            o.x = f2b(b.x); o.y = f2b(b.y); o.z = f2b(b.z); o.w = f2b(b.w);
            *reinterpret_cast<ushort4*>(x0 + idx) = o;
        }
        return;
    }
    __shared__ unsigned lhist[MAXNB];
    __shared__ unsigned lbase[MAXNB];
    __shared__ unsigned lcur[MAXNB];
    __shared__ unsigned gbase[MAXNB];
    __shared__ unsigned perm[CHUNK];
    __shared__ unsigned ws8s[8];
    __shared__ unsigned carry_s;
    const int c = blockIdx.x;
    const int lane = threadIdx.x & 63, w = threadIdx.x >> 6;
    for (int j = threadIdx.x; j < NB; j += 512) lhist[j] = 0u;
    if (threadIdx.x == 0) carry_s = 0u;
    __syncthreads();
    const long long base = (long long)c * CHUNK;
    const int lim = (int)min((long long)CHUNK, (long long)E - base);
    // pass1: local histogram (vectorized)
    {
        const int nv = lim >> 2;
        const int4* d4 = (const int4*)(edst + base);
        for (int i = threadIdx.x; i < nv; i += 512) {
            int4 d = d4[i];
            atomicAdd(&lhist[(unsigned)d.x >> 9], 1u);
            atomicAdd(&lhist[(unsigned)d.y >> 9], 1u);
            atomicAdd(&lhist[(unsigned)d.z >> 9], 1u);
            atomicAdd(&lhist[(unsigned)d.w >> 9], 1u);
        }
        for (int i = (nv << 2) + threadIdx.x; i < lim; i += 512)
            atomicAdd(&lhist[(unsigned)edst[base + i] >> 9], 1u);
    }
    __syncthreads();
    // exclusive scan of lhist -> lbase; init lcur; load gbase
    for (int b0 = 0; b0 < NB; b0 += 512) {
        int j = b0 + (int)threadIdx.x;
        unsigned v = (j < NB) ? lhist[j] : 0u;
        unsigned inc = v;
        #pragma unroll
        for (int d = 1; d < 64; d <<= 1) {
            unsigned t = __shfl_up(inc, d);
            if (lane >= d) inc += t;
        }
        if (lane == 63) ws8s[w] = inc;
        __syncthreads();
        if (threadIdx.x < 8) {
            unsigned x = ws8s[threadIdx.x];
            #pragma unroll
            for (int d = 1; d < 8; d <<= 1) {
                unsigned t = __shfl_up(x, d);
                if ((int)threadIdx.x >= d) x += t;
            }
            ws8s[threadIdx.x] = x;
        }
        __syncthreads();
        unsigned carry = carry_s;
        if (j < NB) {
            unsigned e = carry + ((w == 0) ? 0u : ws8s[w - 1]) + inc - v;
            lbase[j] = e;
            lcur[j]  = e;
            gbase[j] = cnt[(size_t)j * nchunk + c];
        }
        __syncthreads();
        if (threadIdx.x == 511) carry_s = carry + ws8s[7];
        __syncthreads();
    }
    // pass2: local ranks -> perm
    for (int i = threadIdx.x; i < lim; i += 512) {
        unsigned d = (unsigned)edst[base + i];
        unsigned r = atomicAdd(&lcur[d >> 9], 1u);   // LDS atomic
        perm[r] = (unsigned)i;
    }
    __syncthreads();
    // pass3: ordered writes (runs are contiguous; L2-hot random reads)
    for (int t = threadIdx.x; t < lim; t += 512) {
        unsigned i  = perm[t];
        unsigned d  = (unsigned)edst[base + i];
        unsigned s  = (unsigned)esrc[base + i];
        unsigned vb = __float_as_uint(ev[base + i]);
        unsigned b  = d >> 9;
        unsigned dl = d & (NBK - 1);
        unsigned g  = gbase[b] + ((unsigned)t - lbase[b]);
        tmp[g] = ((u64)((dl << 19) | s) << 32) | vb;
    }
}

// ---- pass D (v3): per-bucket counting sort with ordered writes ----
__global__ __launch_bounds__(512)
void p_bsort(const u64* __restrict__ tmp, const unsigned* __restrict__ cnt,
             u64* __restrict__ fin, unsigned* __restrict__ off,
             int E, int N, int NB, int nchunk) {
    __shared__ unsigned c2[NBK];
    __shared__ unsigned o2[NBK];
    __shared__ unsigned ws8s[8];
    __shared__ unsigned perm[PERMCAP];
    const int b = blockIdx.x, tid = threadIdx.x;
    const int lane = tid & 63, w = tid >> 6;
    const unsigned base = cnt[(size_t)b * nchunk];
    const unsigned end  = (b + 1 < NB) ? cnt[(size_t)(b + 1) * nchunk] : (unsigned)E;
    const unsigned m = end - base;
    c2[tid] = 0u;
    __syncthreads();
    for (unsigned i = base + tid; i < end; i += 512)
        atomicAdd(&c2[(unsigned)(tmp[i] >> 51) & (NBK - 1)], 1u);
    __syncthreads();
    // exclusive scan of 512 counters
    unsigned v = c2[tid], inc = v;
    #pragma unroll
    for (int d = 1; d < 64; d <<= 1) { unsigned t = __shfl_up(inc, d); if (lane >= d) inc += t; }
    if (lane == 63) ws8s[w] = inc;
    __syncthreads();
    if (tid < 8) {
        unsigned x = ws8s[tid];
        #pragma unroll
        for (int d = 1; d < 8; d <<= 1) { unsigned t = __shfl_up(x, d); if (tid >= d) x += t; }
        ws8s[tid] = x;
    }
    __syncthreads();
    const unsigned excl = inc - v + ((w == 0) ? 0u : ws8s[w - 1]);
    o2[tid] = excl;                       // local cursor
    int n0 = b * NBK + tid;
    if (n0 < N) off[n0] = base + excl;    // CSR offsets
    if (b == 0 && tid == 0) off[N] = (unsigned)E;
    __syncthreads();
    if (m <= (unsigned)PERMCAP) {
        // pass2: ranks -> perm
        for (unsigned i = base + tid; i < end; i += 512) {
            unsigned dl = (unsigned)(tmp[i] >> 51) & (NBK - 1);
            unsigned r  = atomicAdd(&o2[dl], 1u);  // LDS atomic
            perm[r] = i - base;
        }
        __syncthreads();
        // pass3: ordered streaming writes; random reads stay L2-resident
        for (unsigned t = tid; t < m; t += 512) {
            u64 pk = tmp[base + perm[t]];
            unsigned src = (unsigned)(pk >> 32) & 0x7FFFFu;
            unsigned vb  = (unsigned)pk;
            fin[base + t] = (u64)src | ((u64)vb << 32);
        }
    } else {
        // oversized bucket (statistically negligible): direct scatter
        for (unsigned i = base + tid; i < end; i += 512) {
            u64 pk = tmp[i];
            unsigned dl  = (unsigned)(pk >> 51) & (NBK - 1);
            unsigned src = (unsigned)(pk >> 32) & 0x7FFFFu;
            unsigned vb  = (unsigned)pk;
            unsigned r   = atomicAdd(&o2[dl], 1u);
            fin[base + r] = (u64)src | ((u64)vb << 32);
        }
    }
}

// ---- gather: one wave per dst node, 8 lanes/edge, uint4 x-loads ----
template<int FINAL>
__global__ __launch_bounds__(BLK)
void g_gather(const unsigned* __restrict__ off, const u64* __restrict__ edges,
              const u16* __restrict__ x, u16* __restrict__ hout,
              const float* __restrict__ ue, const float* __restrict__ ie,
              const u16* __restrict__ h1, const u16* __restrict__ h2,
              int n_users, float* __restrict__ out, int N) {
    __shared__ u64 sh[WPB][64];
    const int w    = threadIdx.x >> 6;
    const int lane = threadIdx.x & 63;
    const int node = blockIdx.x * WPB + w;
    if (node >= N) return;
    const int q  = lane >> 3;        // edge slot within group of 8
    const int d8 = lane & 7;         // dims [8*d8, 8*d8+8)
    const unsigned beg = off[node];
    const unsigned end = off[node + 1];
    float a0=0.f,a1=0.f,a2=0.f,a3=0.f,a4=0.f,a5=0.f,a6=0.f,a7=0.f;
    for (unsigned base = beg; base < end; base += 64) {
        const int cnt = (int)min(64u, end - base);
        sh[w][lane] = (lane < cnt) ? __builtin_nontemporal_load(&edges[base + lane])
                                   : 0ull;                 // pad: src=0, val=0
        const int npad = (cnt + 7) & ~7;
        int j = 0;
        for (; j + 32 <= npad; j += 32) {
            u64 p0 = sh[w][j      + q];
            u64 p1 = sh[w][j +  8 + q];
            u64 p2 = sh[w][j + 16 + q];
            u64 p3 = sh[w][j + 24 + q];
            const uint4 x0v = *reinterpret_cast<const uint4*>(x + (size_t)(unsigned)p0 * D + d8 * 8);
            const uint4 x1v = *reinterpret_cast<const uint4*>(x + (size_t)(unsigned)p1 * D + d8 * 8);
            const uint4 x2v = *reinterpret_cast<const uint4*>(x + (size_t)(unsigned)p2 * D + d8 * 8);
            const uint4 x3v = *reinterpret_cast<const uint4*>(x + (size_t)(unsigned)p3 * D + d8 * 8);
            float v0 = __uint_as_float((unsigned)(p0 >> 32));
            float v1 = __uint_as_float((unsigned)(p1 >> 32));
            float v2 = __uint_as_float((unsigned)(p2 >> 32));
            float v3 = __uint_as_float((unsigned)(p3 >> 32));
            a0 += v0*blo(x0v.x); a1 += v0*bhi(x0v.x); a2 += v0*blo(x0v.y); a3 += v0*bhi(x0v.y);
            a4 += v0*blo(x0v.z); a5 += v0*bhi(x0v.z); a6 += v0*blo(x0v.w); a7 += v0*bhi(x0v.w);
            a0 += v1*blo(x1v.x); a1 += v1*bhi(x1v.x); a2 += v1*blo(x1v.y); a3 += v1*bhi(x1v.y);
            a4 += v1*blo(x1v.z); a5 += v1*bhi(x1v.z); a6 += v1*blo(x1v.w); a7 += v1*bhi(x1v.w);
            a0 += v2*blo(x2v.x); a1 += v2*bhi(x2v.x); a2 += v2*blo(x2v.y); a3 += v2*bhi(x2v.y);
            a4 += v2*blo(x2v.z); a5 += v2*bhi(x2v.z); a6 += v2*blo(x2v.w); a7 += v2*bhi(x2v.w);
            a0 += v3*blo(x3v.x); a1 += v3*bhi(x3v.x); a2 += v3*blo(x3v.y); a3 += v3*bhi(x3v.y);
            a4 += v3*blo(x3v.z); a5 += v3*bhi(x3v.z); a6 += v3*blo(x3v.w); a7 += v3*bhi(x3v.w);
        }
        for (; j < npad; j += 8) {
            u64 p = sh[w][j + q];
            const uint4 xv = *reinterpret_cast<const uint4*>(x + (size_t)(unsigned)p * D + d8 * 8);
            float v = __uint_as_float((unsigned)(p >> 32));
            a0 += v*blo(xv.x); a1 += v*bhi(xv.x); a2 += v*blo(xv.y); a3 += v*bhi(xv.y);
            a4 += v*blo(xv.z); a5 += v*bhi(xv.z); a6 += v*blo(xv.w); a7 += v*bhi(xv.w);
        }
    }
    #pragma unroll
    for (int m = 8; m < 64; m <<= 1) {
        a0 += __shfl_xor(a0, m); a1 += __shfl_xor(a1, m);
        a2 += __shfl_xor(a2, m); a3 += __shfl_xor(a3, m);
        a4 += __shfl_xor(a4, m); a5 += __shfl_xor(a5, m);
        a6 += __shfl_xor(a6, m); a7 += __shfl_xor(a7, m);
    }
    if (lane < 8) {
        const size_t o = (size_t)node * D + (size_t)d8 * 8;
        if (FINAL) {
            const float* h0row = (node < n_users) ? (ue + (size_t)node * D)
                                                  : (ie + (size_t)(node - n_users) * D);
            float4 hA = ldf4(h0row + d8 * 8);
            float4 hB = ldf4(h0row + d8 * 8 + 4);
            uint4 r1 = *reinterpret_cast<const uint4*>(h1 + o);
            uint4 r2 = *reinterpret_cast<const uint4*>(h2 + o);
            float4 oA, oB;
            oA.x = (hA.x + blo(r1.x) + blo(r2.x) + a0) * 0.25f;
            oA.y = (hA.y + bhi(r1.x) + bhi(r2.x) + a1) * 0.25f;
            oA.z = (hA.z + blo(r1.y) + blo(r2.y) + a2) * 0.25f;
            oA.w = (hA.w + bhi(r1.y) + bhi(r2.y) + a3) * 0.25f;
            oB.x = (hB.x + blo(r1.z) + blo(r2.z) + a4) * 0.25f;
            oB.y = (hB.y + bhi(r1.z) + bhi(r2.z) + a5) * 0.25f;
            oB.z = (hB.z + blo(r1.w) + blo(r2.w) + a6) * 0.25f;
            oB.w = (hB.w + bhi(r1.w) + bhi(r2.w) + a7) * 0.25f;
            *reinterpret_cast<float4*>(out + o)     = oA;
            *reinterpret_cast<float4*>(out + o + 4) = oB;
        } else {
            uint4 hv;
            hv.x = ((unsigned)f2b(a1) << 16) | f2b(a0);
            hv.y = ((unsigned)f2b(a3) << 16) | f2b(a2);
            hv.z = ((unsigned)f2b(a5) << 16) | f2b(a4);
            hv.w = ((unsigned)f2b(a7) << 16) | f2b(a6);
            *reinterpret_cast<uint4*>(hout + o) = hv;
        }
    }
}

// ---- fallback: atomic push path ----
__global__ __launch_bounds__(BLK)
void scatter_first(const int* __restrict__ esrc, const int* __restrict__ edst,
                   const float* __restrict__ ev,
                   const float* __restrict__ ue, const float* __restrict__ ie,
                   int n_users, float* __restrict__ y, int n_edges) {
    long long t = (long long)blockIdx.x * BLK + threadIdx.x;
    int e = (int)(t >> 4);
    if (e >= n_edges) return;
    int lane = (int)(threadIdx.x & 15);
    int s = esrc[e]; int d = edst[e]; float v = ev[e];
    const float* xrow = (s < n_users) ? (ue + (size_t)s * D)
                                      : (ie + (size_t)(s - n_users) * D);
    float4 xs = ldf4(xrow + lane * 4);
    float* yp = y + (size_t)d * D + lane * 4;
    unsafeAtomicAdd(yp + 0, v * xs.x);
    unsafeAtomicAdd(yp + 1, v * xs.y);
    unsafeAtomicAdd(yp + 2, v * xs.z);
    unsafeAtomicAdd(yp + 3, v * xs.w);
}

__global__ __launch_bounds__(BLK)
void scatter_gen(const int* __restrict__ esrc, const int* __restrict__ edst,
                 const float* __restrict__ ev, const float* __restrict__ x,
                 float* __restrict__ y, int n_edges) {
    long long t = (long long)blockIdx.x * BLK + threadIdx.x;
    int e = (int)(t >> 4);
    if (e >= n_edges) return;
    int lane = (int)(threadIdx.x & 15);
    int s = esrc[e]; int d = edst[e]; float v = ev[e];
    float4 xs = ldf4(x + (size_t)s * D + lane * 4);
    float* yp = y + (size_t)d * D + lane * 4;
    unsafeAtomicAdd(yp + 0, v * xs.x);
    unsafeAtomicAdd(yp + 1, v * xs.y);
    unsafeAtomicAdd(yp + 2, v * xs.z);
    unsafeAtomicAdd(yp + 3, v * xs.w);
}

__global__ __launch_bounds__(BLK)
void combine4(const float* __restrict__ ue, const float* __restrict__ ie,
              const float* __restrict__ h1, const float* __restrict__ h2,
              const float* __restrict__ h3, float* __restrict__ out,
              long long u_elems, long long total4) {
    long long i = (long long)blockIdx.x * BLK + threadIdx.x;
    if (i >= total4) return;
    long long idx = i * 4;
    float4 b  = (idx < u_elems) ? ldf4(ue + idx) : ldf4(ie + (idx - u_elems));
    float4 a1 = ldf4(h1 + idx);
    float4 a2 = ldf4(h2 + idx);
    float4 a3 = ldf4(h3 + idx);
    float4 r;
    r.x = (b.x + a1.x + a2.x + a3.x) * 0.25f;
    r.y = (b.y + a1.y + a2.y + a3.y) * 0.25f;
    r.z = (b.z + a1.z + a2.z + a3.z) * 0.25f;
    r.w = (b.w + a1.w + a2.w + a3.w) * 0.25f;
    *reinterpret_cast<float4*>(out + idx) = r;
}

// ---- launch ----
extern "C" void kernel_launch(void* const* d_in, const int* in_sizes, int n_in,
                              void* d_out, int out_size, void* d_ws, size_t ws_size,
                              hipStream_t stream) {
    const float* ue   = (const float*)d_in[0];
    const float* ie   = (const float*)d_in[1];
    const int*   esrc = (const int*)d_in[2];
    const int*   edst = (const int*)d_in[3];
    const float* ev   = (const float*)d_in[4];

    const int n_users = in_sizes[0] / D;
    const int n_items = in_sizes[1] / D;
    const int E       = in_sizes[2];
    const int N       = n_users + n_items;
    const long long elems = (long long)N * D;
    const size_t bufBytes = (size_t)elems * sizeof(float);

    const int NB     = (N + NBK - 1) / NBK;
    const int nchunk = (E + CHUNK - 1) / CHUNK;
    const int M      = NB * nchunk;
    const int nb1    = (M + 1023) / 1024;

    const long long total4  = elems / 4;
    const int vecBlocks     = (int)((total4 + BLK - 1) / BLK);
    const long long u_elems = (long long)n_users * D;
    const int gBlocks       = (N + WPB - 1) / WPB;
    float* out = (float*)d_out;

    // ws layout: h1b aliases tmp (tmp dead after p_bsort);
    //            x0 aliases h2b (x0 dead after gather-1, h2b written by gather-2).
    const size_t tmpBytes = (size_t)E * 8;
    const size_t hbBytes  = (size_t)elems * 2;
    const size_t r1Bytes  = tmpBytes > hbBytes ? tmpBytes : hbBytes;
    char* p = (char*)d_ws;
    u64* tmp = (u64*)p;  u16* h1b = (u16*)p;  p += r1Bytes;
    u64*      fin  = (u64*)p;                 p += tmpBytes;
    u16*      x0   = (u16*)p; u16* h2b = x0;  p += hbBytes;
    unsigned* cnt  = (unsigned*)p;            p += (size_t)M * 4;
    unsigned* off  = (unsigned*)p;            p += ((size_t)N + 1) * 4;
    unsigned* bsum = (unsigned*)p;            p += (size_t)nb1 * 4;
    unsigned* bsumX= (unsigned*)p;            p += ((size_t)nb1 + 1) * 4;
    const size_t need = (size_t)(p - (char*)d_ws);

    if (ws_size >= need && NB <= MAXNB && N < (1 << 19)) {
        // CSR build (atomic-free, write-coalesced)
        p_hist<<<nchunk, 512, 0, stream>>>(edst, cnt, E, NB, nchunk);
        p_reduce<<<nb1, 1024, 0, stream>>>(cnt, bsum, M);
        k_scan<<<1, 1024, 0, stream>>>(bsum, bsumX, nb1);
        p_scanapply<<<nb1, 1024, 0, stream>>>(cnt, bsumX, M);
        p_part<<<nchunk + CVTB, 512, 0, stream>>>(esrc, edst, ev, cnt, tmp,
                                                  ue, ie, x0, u_elems, total4,
                                                  E, NB, nchunk);
        p_bsort<<<NB, 512, 0, stream>>>(tmp, cnt, fin, off, E, N, NB, nchunk);
        // 3 gather layers (layer 3 fused with final average)
        g_gather<0><<<gBlocks, BLK, 0, stream>>>(off, fin, x0, h1b, ue, ie,
                                                 nullptr, nullptr, n_users, nullptr, N);
        g_gather<0><<<gBlocks, BLK, 0, stream>>>(off, fin, h1b, h2b, ue, ie,
                                                 nullptr, nullptr, n_users, nullptr, N);
        g_gather<1><<<gBlocks, BLK, 0, stream>>>(off, fin, h2b, nullptr, ue, ie,
                                                 h1b, h2b, n_users, out, N);
    } else {
        // fallback: atomic push path (3 * bufBytes)
        float* h1 = (float*)d_ws;
        float* h2 = (float*)((char*)d_ws + bufBytes);
        float* h3 = (float*)((char*)d_ws + 2 * bufBytes);
        const int scatterBlocks = (int)(((long long)E * 16 + BLK - 1) / BLK);
        hipMemsetAsync(h1, 0, bufBytes, stream);
        hipMemsetAsync(h2, 0, bufBytes, stream);
        hipMemsetAsync(h3, 0, bufBytes, stream);
        scatter_first<<<scatterBlocks, BLK, 0, stream>>>(esrc, edst, ev, ue, ie,
                                                         n_users, h1, E);
        scatter_gen<<<scatterBlocks, BLK, 0, stream>>>(esrc, edst, ev, h1, h2, E);
        scatter_gen<<<scatterBlocks, BLK, 0, stream>>>(esrc, edst, ev, h2, h3, E);
        combine4<<<vecBlocks, BLK, 0, stream>>>(ue, ie, h1, h2, h3, out,
                                                u_elems, total4);
    }
}